// Round 4
// baseline (141.617 us; speedup 1.0000x reference)
//
#include <hip/hip_runtime.h>
#include <math.h>

// B=2048, L=64. out = sum(kl) + (BETA-1)*mean_i(log_qz_i - log_qz_product_i)
// lp2[i,j,l] = lp/ln2 = a2*d^2 + b2, d = z_i_l - m_j_l, a2 = -0.5/ln2*exp(-lv) < 0
// Single-pass LSE with constant shift BVAL (valid since lp2 <= b2 << BVAL).
// Horner: lp2 - BVAL = fma(fma(z, a2, c1), z, c0'), c1=-2*a2*m, c0'=a2*m^2+b2-BVAL.
//
// Round-4: pk fp32 reverted (gfx950 v_pk_fma_f32 is half-rate -> null; measured
// r3). K3 already at core floor (2 fma + exp2 + add = 14cy/elem-wave). K2 was
// the bloat: block-uniform z tile read via ds_read_b128 (20us/CU LDS pipe) +
// 4.19M redundant z^2 muls. Now: k1 writes transposed ZT (z) and ZSQT (z^2)
// rows; K2 reads them with uniform-address loads (scalarized to s_load) and
// does only the 16 fma/k core. zsh LDS tile deleted. Bit-identical output
// (same values, same order; z^2 precomputed with same v_mul rounding).

#define NB 2048
#define NL 64
#define NE (NB * NL)
#define BVAL 12.0f

__device__ __forceinline__ float wredsum(float v) {
#pragma unroll
  for (int o = 32; o; o >>= 1) v += __shfl_xor(v, o, 64);
  return v;
}
__device__ __forceinline__ float wredmax(float v) {
#pragma unroll
  for (int o = 32; o; o >>= 1) v = fmaxf(v, __shfl_xor(v, o, 64));
  return v;
}

// K1: packed Horner coeffs (a2,c1 | c0') for the K3 path, interleaved (a2,c1)
// transposed array + qc2 for the K2 path, transposed z / z^2 rows for K2's
// scalar-load path, per-block kl partial sums.
__global__ __launch_bounds__(256) void k1_pre(const float* __restrict__ kl,
                                              const float* __restrict__ zm,
                                              const float* __restrict__ zlv,
                                              const float* __restrict__ zs,
                                              float2* __restrict__ PK2A,
                                              float* __restrict__ PK2B,
                                              float2* __restrict__ AM2T,
                                              float* __restrict__ ZT,
                                              float* __restrict__ ZSQT,
                                              float* __restrict__ QC2,
                                              float* __restrict__ KLP) {
  const float INVLN2 = 1.4426950408889634f;
  const float LOG2PI = 1.8378770664093453f;
  int tid = threadIdx.x;
  int e = blockIdx.x * 256 + tid;  // < NE
  int j = e >> 6, l = e & 63;
  float lv = zlv[e], m = zm[e];
  float a2 = -0.5f * INVLN2 * __expf(-lv);
  float b2 = -0.5f * INVLN2 * (lv + LOG2PI);
  float c1 = -2.0f * a2 * m;
  float c0 = fmaf(a2 * m, m, b2);  // true a2*m^2 + b2
  PK2A[e] = make_float2(a2, c1);
  PK2B[e] = c0 - BVAL;
  AM2T[l * NB + j] = make_float2(a2, c1);
  float z = zs[e];
  ZT[l * NB + j] = z;        // ZT[l][i]  (here j indexes the zs row = i)
  ZSQT[l * NB + j] = z * z;  // same rounding as in-loop zk*zk
  float q = wredsum(c0);     // sum_l (a2 m^2 + b2) for this j (one j per wave)
  if (l == 0) QC2[j] = q;
  float ks = wredsum(kl[e]);
  __shared__ float sk[4];
  if (l == 0) sk[tid >> 6] = ks;
  __syncthreads();
  if (tid == 0) KLP[blockIdx.x] = sk[0] + sk[1] + sk[2] + sk[3];
}

// Fused K2+K3 (independent phases, same grid, no cross-block comm).
// grid (8 j-chunks, 256 i-tiles), 256 thr.
// K2 phase: thread = one j, 8 i's; z/z^2 rows are block-uniform -> uniform
// loads (s_load), one SGPR operand per v_fma; no LDS, no in-loop z^2 mul.
// K3 phase: thread = (wave w, lane l); 64 j's per wave, 8 i's per thread.
// Linear block id = jc + 8*it -> XCD = bid%8 = jc: each XCD streams only its
// own 256KB jc-chunk of PK2 (L2 locality); keep this mapping.
__global__ __launch_bounds__(256) void k23(const float* __restrict__ zs,
                                           const float2* __restrict__ AM2T,
                                           const float* __restrict__ ZT,
                                           const float* __restrict__ ZSQT,
                                           const float* __restrict__ QC2,
                                           const float2* __restrict__ PK2A,
                                           const float* __restrict__ PK2B,
                                           float* __restrict__ TPM,
                                           float* __restrict__ TPS,
                                           float* __restrict__ SP) {
  int jc = blockIdx.x;      // 0..7
  int i0 = blockIdx.y * 8;  // i tile base
  int tid = threadIdx.x;
  int w = tid >> 6, l = tid & 63;
  int j = jc * 256 + tid;

  // ---------------- K2 phase (scalar fma core, uniform z loads) ----------
  float q = QC2[j];
  float accv[8];
#pragma unroll
  for (int r = 0; r < 8; ++r) accv[r] = q;
  for (int k = 0; k < 64; ++k) {
    float2 am = AM2T[k * NB + j];  // (a2, c1) per-thread
    const float4* zt4 = (const float4*)(ZT + k * NB + i0);    // uniform addr
    const float4* zq4 = (const float4*)(ZSQT + k * NB + i0);  // uniform addr
    float4 za = zt4[0], zb = zt4[1];
    float4 qa = zq4[0], qb = zq4[1];
    float zk[8] = {za.x, za.y, za.z, za.w, zb.x, zb.y, zb.z, zb.w};
    float zz[8] = {qa.x, qa.y, qa.z, qa.w, qb.x, qb.y, qb.z, qb.w};
#pragma unroll
    for (int r = 0; r < 8; ++r) {
      accv[r] = fmaf(zz[r], am.x, accv[r]);  // == fmaf(zk*zk, a2, acc)
      accv[r] = fmaf(zk[r], am.y, accv[r]);  // == fmaf(zk,    c1, acc)
    }
  }
  __shared__ float lm[4][8], ls[4][8];
  float Mt[8];
#pragma unroll
  for (int r = 0; r < 8; ++r) {
    float mx = wredmax(accv[r]);
    if (l == 0) lm[w][r] = mx;
  }
  __syncthreads();
#pragma unroll
  for (int r = 0; r < 8; ++r)
    Mt[r] = fmaxf(fmaxf(lm[0][r], lm[1][r]), fmaxf(lm[2][r], lm[3][r]));
#pragma unroll
  for (int r = 0; r < 8; ++r) {
    float ss = wredsum(__builtin_amdgcn_exp2f(accv[r] - Mt[r]));
    if (l == 0) ls[w][r] = ss;
  }
  __syncthreads();
  if (tid == 0) {
#pragma unroll
    for (int r = 0; r < 8; ++r) {
      TPM[(i0 + r) * 8 + jc] = Mt[r];
      TPS[(i0 + r) * 8 + jc] = ls[0][r] + ls[1][r] + ls[2][r] + ls[3][r];
    }
  }

  // ---------------- K3 phase (scalar, 12B packed coeffs) -----------------
  float zr[8];
#pragma unroll
  for (int r = 0; r < 8; ++r) zr[r] = zs[(i0 + r) * NL + l];
  float S[8];
#pragma unroll
  for (int r = 0; r < 8; ++r) S[r] = 0.0f;
  const float2* pa = PK2A + (size_t)(jc * 256 + w * 64) * NL + l;
  const float* pb = PK2B + (size_t)(jc * 256 + w * 64) * NL + l;
#pragma unroll 4
  for (int jj = 0; jj < 64; ++jj) {
    float2 c01 = pa[(size_t)jj * NL];
    float c2 = pb[(size_t)jj * NL];
#pragma unroll
    for (int r = 0; r < 8; ++r) {
      float lp2 = fmaf(fmaf(zr[r], c01.x, c01.y), zr[r], c2);
      S[r] += __builtin_amdgcn_exp2f(lp2);
    }
  }
  __shared__ float lss[4][8][64];
#pragma unroll
  for (int r = 0; r < 8; ++r) lss[w][r][l] = S[r];
  __syncthreads();
  for (int pp = tid; pp < 512; pp += 256) {
    int r = pp >> 6, ll = pp & 63;
    float Sc = lss[0][r][ll] + lss[1][r][ll] + lss[2][r][ll] + lss[3][r][ll];
    SP[((size_t)jc * NB + (i0 + r)) * NL + ll] = Sc;
  }
}

// K4: per-i: sum 8 j-chunk partials per (i,l) -> log2, sum over l (+64*BVAL),
// LSE-merge the 8 t-chunks -> log_qz; write per-i contribution. 1 wave per i.
__global__ __launch_bounds__(256) void k4_fin(const float* __restrict__ SP,
                                              const float* __restrict__ TPM,
                                              const float* __restrict__ TPS,
                                              float* __restrict__ PERI) {
  int tid = threadIdx.x;
  int w = tid >> 6, l = tid & 63;
  int i = blockIdx.x * 4 + w;
  float S = 0.0f;
#pragma unroll
  for (int s = 0; s < 8; ++s) S += SP[((size_t)s * NB + i) * NL + l];
  float val = __builtin_amdgcn_logf(S);  // log2
  float lqp2 = wredsum(val) + 64.0f * BVAL;
  float tm = (l < 8) ? TPM[i * 8 + l] : -1e30f;
  float ts = (l < 8) ? TPS[i * 8 + l] : 0.0f;
  float Mt = wredmax(tm);
  float St = wredsum(ts * __builtin_amdgcn_exp2f(tm - Mt));
  float lqz2 = Mt + __builtin_amdgcn_logf(St);
  if (l == 0) PERI[i] = lqz2 - lqp2;
}

// K5: final scalar. sum KLP[512], sum PERI[2048].
__global__ __launch_bounds__(256) void k5_out(const float* __restrict__ KLP,
                                              const float* __restrict__ PERI,
                                              float* __restrict__ out) {
  int tid = threadIdx.x;
  float a = 0.0f, b = 0.0f;
  for (int x = tid; x < 512; x += 256) a += KLP[x];
  for (int x = tid; x < 2048; x += 256) b += PERI[x];
  float ra = wredsum(a), rb = wredsum(b);
  __shared__ float sa[4], sb[4];
  if ((tid & 63) == 0) {
    sa[tid >> 6] = ra;
    sb[tid >> 6] = rb;
  }
  __syncthreads();
  if (tid == 0) {
    const float LN2 = 0.6931471805599453f;
    float ka = sa[0] + sa[1] + sa[2] + sa[3];
    float kb = sb[0] + sb[1] + sb[2] + sb[3];
    out[0] = ka + 5.0f * LN2 * kb * (1.0f / (float)NB);
  }
}

extern "C" void kernel_launch(void* const* d_in, const int* in_sizes, int n_in,
                              void* d_out, int out_size, void* d_ws, size_t ws_size,
                              hipStream_t stream) {
  const float* kl = (const float*)d_in[0];
  const float* zm = (const float*)d_in[1];
  const float* zlv = (const float*)d_in[2];
  const float* zs = (const float*)d_in[3];
  float* ws = (float*)d_ws;

  float* PK2A = ws;                 // 2*NE
  float* PK2B = PK2A + 2 * NE;      // NE
  float* AM2T = PK2B + NE;          // 2*NE (interleaved a2,c1 transposed)
  float* ZT = AM2T + 2 * NE;        // NE   (z transposed  [l][i])
  float* ZSQT = ZT + NE;            // NE   (z^2 transposed [l][i])
  float* QC2 = ZSQT + NE;           // NB
  float* SP = QC2 + NB;             // 8*NE
  float* TPM = SP + 8 * NE;         // NB*8
  float* TPS = TPM + NB * 8;        // NB*8
  float* KLP = TPS + NB * 8;        // 512
  float* PERI = KLP + 512;          // NB     (total ~8.4 MB)

  k1_pre<<<NE / 256, 256, 0, stream>>>(kl, zm, zlv, zs, (float2*)PK2A, PK2B,
                                       (float2*)AM2T, ZT, ZSQT, QC2, KLP);
  k23<<<dim3(8, NB / 8), 256, 0, stream>>>(zs, (const float2*)AM2T, ZT, ZSQT,
                                           QC2, (const float2*)PK2A, PK2B, TPM,
                                           TPS, SP);
  k4_fin<<<NB / 4, 256, 0, stream>>>(SP, TPM, TPS, PERI);
  k5_out<<<1, 256, 0, stream>>>(KLP, PERI, (float*)d_out);
}

// Round 5
// 134.394 us; speedup vs baseline: 1.0537x; 1.0537x over previous
//
#include <hip/hip_runtime.h>
#include <math.h>

// B=2048, L=64. out = sum(kl) + (BETA-1)*mean_i(log_qz_i - log_qz_product_i)
// lp2[i,j,l] = lp/ln2 = a2*d^2 + b2, d = z_i_l - m_j_l, a2 = -0.5/ln2*exp(-lv) < 0
// Single-pass LSE with constant shift BVAL (valid since lp2 <= b2 << BVAL).
// Horner: lp2 - BVAL = fma(fma(z, a2, c1), z, c0'), c1=-2*a2*m, c0'=a2*m^2+b2-BVAL.
//
// Round-5: revert round-4's scalar-load K2 (compiler emitted per-lane broadcast
// VMEM, FETCH 3.4x, -8%). Back to round-2 math (best: k23=71us), one new lever:
// PHASE-SPLIT BLOCKS. K2 (fma-heavy, trans idle) and K3 (exp2-heavy, VALU ~40%
// idle) run as *separate blocks* of one kernel: grid (8,512), phase=y&1.
// Dispatch interleaves phases so each CU co-hosts both -> VALU and trans pipes
// fill each other's bubbles; mid-kernel barriers between phases gone.
// jc=blockIdx.x keeps XCD=lin%8=jc -> per-XCD L2 locality of PK2/AM2T intact.
// Same values, same reduction order as round-2 -> bit-identical output.

#define NB 2048
#define NL 64
#define NE (NB * NL)
#define BVAL 12.0f

__device__ __forceinline__ float wredsum(float v) {
#pragma unroll
  for (int o = 32; o; o >>= 1) v += __shfl_xor(v, o, 64);
  return v;
}
__device__ __forceinline__ float wredmax(float v) {
#pragma unroll
  for (int o = 32; o; o >>= 1) v = fmaxf(v, __shfl_xor(v, o, 64));
  return v;
}

// K1: packed Horner coeffs (a2,c1 | c0') for the K3 path, interleaved (a2,c1)
// transposed array + qc2 for the K2 path, per-block kl partial sums.
__global__ __launch_bounds__(256) void k1_pre(const float* __restrict__ kl,
                                              const float* __restrict__ zm,
                                              const float* __restrict__ zlv,
                                              float2* __restrict__ PK2A,
                                              float* __restrict__ PK2B,
                                              float2* __restrict__ AM2T,
                                              float* __restrict__ QC2,
                                              float* __restrict__ KLP) {
  const float INVLN2 = 1.4426950408889634f;
  const float LOG2PI = 1.8378770664093453f;
  int tid = threadIdx.x;
  int e = blockIdx.x * 256 + tid;  // < NE
  int j = e >> 6, l = e & 63;
  float lv = zlv[e], m = zm[e];
  float a2 = -0.5f * INVLN2 * __expf(-lv);
  float b2 = -0.5f * INVLN2 * (lv + LOG2PI);
  float c1 = -2.0f * a2 * m;
  float c0 = fmaf(a2 * m, m, b2);  // true a2*m^2 + b2
  PK2A[e] = make_float2(a2, c1);
  PK2B[e] = c0 - BVAL;
  AM2T[l * NB + j] = make_float2(a2, c1);
  float q = wredsum(c0);  // sum_l (a2 m^2 + b2) for this j (one j per wave)
  if (l == 0) QC2[j] = q;
  float ks = wredsum(kl[e]);
  __shared__ float sk[4];
  if (l == 0) sk[tid >> 6] = ks;
  __syncthreads();
  if (tid == 0) KLP[blockIdx.x] = sk[0] + sk[1] + sk[2] + sk[3];
}

// Phase-split fused K2/K3. grid (8 j-chunks, 512), 256 thr.
// y&1==0 -> K2 block for i-tile y>>1 (thread = one j, 8 i's, zsh LDS tile).
// y&1==1 -> K3 block for i-tile y>>1 (thread = (w,l); 64 j's/wave, 8 i's).
// Linear id = jc + 8*y -> XCD = jc for every block: each XCD streams only its
// own 256KB jc-chunk of PK2/AM2T; consecutive ids alternate phase -> each CU
// co-hosts fma-heavy K2 blocks and exp2-heavy K3 blocks (pipe overlap).
__global__ __launch_bounds__(256) void k23(const float* __restrict__ zs,
                                           const float2* __restrict__ AM2T,
                                           const float* __restrict__ QC2,
                                           const float2* __restrict__ PK2A,
                                           const float* __restrict__ PK2B,
                                           float* __restrict__ TPM,
                                           float* __restrict__ TPS,
                                           float* __restrict__ SP) {
  int jc = blockIdx.x;  // 0..7
  int y = blockIdx.y;   // 0..511
  int i0 = (y >> 1) * 8;
  int tid = threadIdx.x;
  int w = tid >> 6, l = tid & 63;

  if ((y & 1) == 0) {
    // ---------------- K2 block (identical math/order to round-2) ----------
    int j = jc * 256 + tid;
    __shared__ float zsh[64][8];  // [k][r]
    if (tid < 128) {
      int k = tid >> 1, r0 = (tid & 1) * 4;
#pragma unroll
      for (int r = 0; r < 4; ++r) zsh[k][r0 + r] = zs[(i0 + r0 + r) * NL + k];
    }
    __syncthreads();
    float accv[8];
    float q = QC2[j];
#pragma unroll
    for (int r = 0; r < 8; ++r) accv[r] = q;
    for (int k = 0; k < 64; ++k) {
      float2 am = AM2T[k * NB + j];  // (a2, c1)
      const float4* z4 = (const float4*)&zsh[k][0];  // wave-uniform -> bcast
      float4 za = z4[0], zb = z4[1];
      float zk[8] = {za.x, za.y, za.z, za.w, zb.x, zb.y, zb.z, zb.w};
#pragma unroll
      for (int r = 0; r < 8; ++r) {
        accv[r] = fmaf(zk[r] * zk[r], am.x, accv[r]);
        accv[r] = fmaf(zk[r], am.y, accv[r]);
      }
    }
    __shared__ float lm[4][8], ls[4][8];
    float Mt[8];
#pragma unroll
    for (int r = 0; r < 8; ++r) {
      float mx = wredmax(accv[r]);
      if (l == 0) lm[w][r] = mx;
    }
    __syncthreads();
#pragma unroll
    for (int r = 0; r < 8; ++r)
      Mt[r] = fmaxf(fmaxf(lm[0][r], lm[1][r]), fmaxf(lm[2][r], lm[3][r]));
#pragma unroll
    for (int r = 0; r < 8; ++r) {
      float ss = wredsum(__builtin_amdgcn_exp2f(accv[r] - Mt[r]));
      if (l == 0) ls[w][r] = ss;
    }
    __syncthreads();
    if (tid == 0) {
#pragma unroll
      for (int r = 0; r < 8; ++r) {
        TPM[(i0 + r) * 8 + jc] = Mt[r];
        TPS[(i0 + r) * 8 + jc] = ls[0][r] + ls[1][r] + ls[2][r] + ls[3][r];
      }
    }
  } else {
    // ---------------- K3 block (identical math/order to round-2) ----------
    float zr[8];
#pragma unroll
    for (int r = 0; r < 8; ++r) zr[r] = zs[(i0 + r) * NL + l];
    float S[8];
#pragma unroll
    for (int r = 0; r < 8; ++r) S[r] = 0.0f;
    const float2* pa = PK2A + (size_t)(jc * 256 + w * 64) * NL + l;
    const float* pb = PK2B + (size_t)(jc * 256 + w * 64) * NL + l;
#pragma unroll 4
    for (int jj = 0; jj < 64; ++jj) {
      float2 c01 = pa[(size_t)jj * NL];
      float c2 = pb[(size_t)jj * NL];
#pragma unroll
      for (int r = 0; r < 8; ++r) {
        float lp2 = fmaf(fmaf(zr[r], c01.x, c01.y), zr[r], c2);
        S[r] += __builtin_amdgcn_exp2f(lp2);
      }
    }
    __shared__ float lss[4][8][64];
#pragma unroll
    for (int r = 0; r < 8; ++r) lss[w][r][l] = S[r];
    __syncthreads();
    for (int pp = tid; pp < 512; pp += 256) {
      int r = pp >> 6, ll = pp & 63;
      float Sc = lss[0][r][ll] + lss[1][r][ll] + lss[2][r][ll] + lss[3][r][ll];
      SP[((size_t)jc * NB + (i0 + r)) * NL + ll] = Sc;
    }
  }
}

// K4: per-i: sum 8 j-chunk partials per (i,l) -> log2, sum over l (+64*BVAL),
// LSE-merge the 8 t-chunks -> log_qz; write per-i contribution. 1 wave per i.
__global__ __launch_bounds__(256) void k4_fin(const float* __restrict__ SP,
                                              const float* __restrict__ TPM,
                                              const float* __restrict__ TPS,
                                              float* __restrict__ PERI) {
  int tid = threadIdx.x;
  int w = tid >> 6, l = tid & 63;
  int i = blockIdx.x * 4 + w;
  float S = 0.0f;
#pragma unroll
  for (int s = 0; s < 8; ++s) S += SP[((size_t)s * NB + i) * NL + l];
  float val = __builtin_amdgcn_logf(S);  // log2
  float lqp2 = wredsum(val) + 64.0f * BVAL;
  float tm = (l < 8) ? TPM[i * 8 + l] : -1e30f;
  float ts = (l < 8) ? TPS[i * 8 + l] : 0.0f;
  float Mt = wredmax(tm);
  float St = wredsum(ts * __builtin_amdgcn_exp2f(tm - Mt));
  float lqz2 = Mt + __builtin_amdgcn_logf(St);
  if (l == 0) PERI[i] = lqz2 - lqp2;
}

// K5: final scalar. sum KLP[512], sum PERI[2048].
__global__ __launch_bounds__(256) void k5_out(const float* __restrict__ KLP,
                                              const float* __restrict__ PERI,
                                              float* __restrict__ out) {
  int tid = threadIdx.x;
  float a = 0.0f, b = 0.0f;
  for (int x = tid; x < 512; x += 256) a += KLP[x];
  for (int x = tid; x < 2048; x += 256) b += PERI[x];
  float ra = wredsum(a), rb = wredsum(b);
  __shared__ float sa[4], sb[4];
  if ((tid & 63) == 0) {
    sa[tid >> 6] = ra;
    sb[tid >> 6] = rb;
  }
  __syncthreads();
  if (tid == 0) {
    const float LN2 = 0.6931471805599453f;
    float ka = sa[0] + sa[1] + sa[2] + sa[3];
    float kb = sb[0] + sb[1] + sb[2] + sb[3];
    out[0] = ka + 5.0f * LN2 * kb * (1.0f / (float)NB);
  }
}

extern "C" void kernel_launch(void* const* d_in, const int* in_sizes, int n_in,
                              void* d_out, int out_size, void* d_ws, size_t ws_size,
                              hipStream_t stream) {
  const float* kl = (const float*)d_in[0];
  const float* zm = (const float*)d_in[1];
  const float* zlv = (const float*)d_in[2];
  const float* zs = (const float*)d_in[3];
  float* ws = (float*)d_ws;

  float* PK2A = ws;                 // 2*NE
  float* PK2B = PK2A + 2 * NE;      // NE
  float* AM2T = PK2B + NE;          // 2*NE (interleaved a2,c1 transposed)
  float* QC2 = AM2T + 2 * NE;       // NB
  float* SP = QC2 + NB;             // 8*NE
  float* TPM = SP + 8 * NE;         // NB*8
  float* TPS = TPM + NB * 8;        // NB*8
  float* KLP = TPS + NB * 8;        // 512
  float* PERI = KLP + 512;          // NB     (total ~7.3 MB)

  k1_pre<<<NE / 256, 256, 0, stream>>>(kl, zm, zlv, (float2*)PK2A, PK2B,
                                       (float2*)AM2T, QC2, KLP);
  k23<<<dim3(8, 2 * (NB / 8)), 256, 0, stream>>>(zs, (const float2*)AM2T, QC2,
                                                 (const float2*)PK2A, PK2B,
                                                 TPM, TPS, SP);
  k4_fin<<<NB / 4, 256, 0, stream>>>(SP, TPM, TPS, PERI);
  k5_out<<<1, 256, 0, stream>>>(KLP, PERI, (float*)d_out);
}

// Round 6
// 128.406 us; speedup vs baseline: 1.1029x; 1.0466x over previous
//
#include <hip/hip_runtime.h>
#include <math.h>

// B=2048, L=64. out = sum(kl) + (BETA-1)*mean_i(log_qz_i - log_qz_product_i)
// lp2[i,j,l] = lp/ln2 = a2*d^2 + b2, d = z_i_l - m_j_l, a2 = -0.5/ln2*exp(-lv) < 0
// Single-pass LSE with constant shift BVAL (valid since lp2 <= b2 << BVAL).
// Horner: lp2 - BVAL = fma(fma(z, a2, c1), z, c0'), c1=-2*a2*m, c0'=a2*m^2+b2-BVAL.
//
// Round-6: consolidation on the round-2 structure (best measured: k23=71.4us).
// Structural rearrangements (pk f32 r3, scalar-loads r4, phase-split r5) all
// failed -> round-2's sequential K2+K3 with natural cross-block skew is the
// schedule optimum. This round strips redundant instructions only:
//  - K2: z^2 staged in LDS (2 muls/thread vs 512; same v_mul rounding),
//        A2T/MA2T merged into one interleaved float2 load (64 vs 128 loads).
//  - K3: coeffs back to one float4 load/jj (issue slots scarce, L2 bytes not).
// Same values, same reduction order -> bit-identical output.

#define NB 2048
#define NL 64
#define NE (NB * NL)
#define BVAL 12.0f

__device__ __forceinline__ float wredsum(float v) {
#pragma unroll
  for (int o = 32; o; o >>= 1) v += __shfl_xor(v, o, 64);
  return v;
}
__device__ __forceinline__ float wredmax(float v) {
#pragma unroll
  for (int o = 32; o; o >>= 1) v = fmaxf(v, __shfl_xor(v, o, 64));
  return v;
}

// K1: packed Horner coeffs (a2,c1,c0',0) for the K3 path, interleaved (a2,c1)
// transposed array + qc2 for the K2 path, per-block kl partial sums.
__global__ __launch_bounds__(256) void k1_pre(const float* __restrict__ kl,
                                              const float* __restrict__ zm,
                                              const float* __restrict__ zlv,
                                              float4* __restrict__ PK2,
                                              float2* __restrict__ AM2T,
                                              float* __restrict__ QC2,
                                              float* __restrict__ KLP) {
  const float INVLN2 = 1.4426950408889634f;
  const float LOG2PI = 1.8378770664093453f;
  int tid = threadIdx.x;
  int e = blockIdx.x * 256 + tid;  // < NE
  int j = e >> 6, l = e & 63;
  float lv = zlv[e], m = zm[e];
  float a2 = -0.5f * INVLN2 * __expf(-lv);
  float b2 = -0.5f * INVLN2 * (lv + LOG2PI);
  float c1 = -2.0f * a2 * m;
  float c0 = fmaf(a2 * m, m, b2);  // true a2*m^2 + b2
  PK2[e] = make_float4(a2, c1, c0 - BVAL, 0.0f);
  AM2T[l * NB + j] = make_float2(a2, c1);
  float q = wredsum(c0);  // sum_l (a2 m^2 + b2) for this j (one j per wave)
  if (l == 0) QC2[j] = q;
  float ks = wredsum(kl[e]);
  __shared__ float sk[4];
  if (l == 0) sk[tid >> 6] = ks;
  __syncthreads();
  if (tid == 0) KLP[blockIdx.x] = sk[0] + sk[1] + sk[2] + sk[3];
}

// Fused K2+K3 (independent phases, same grid, no cross-block comm).
// grid (8 j-chunks, 256 i-tiles), 256 thr.
// K2 phase: thread = one j, 8 i's; z and z^2 tiles staged in LDS (z^2 computed
// once at staging, not 512x per thread in-loop); block LSE over 256-j chunk.
// K3 phase: thread = (wave w, lane l); 64 j's per wave, 8 i's per thread.
// Linear block id = jc + 8*it -> XCD = bid%8 = jc: each XCD streams only its
// own jc-chunk of PK2/AM2T (L2 locality); keep this mapping.
__global__ __launch_bounds__(256) void k23(const float* __restrict__ zs,
                                           const float2* __restrict__ AM2T,
                                           const float* __restrict__ QC2,
                                           const float4* __restrict__ PK2,
                                           float* __restrict__ TPM,
                                           float* __restrict__ TPS,
                                           float* __restrict__ SP) {
  int jc = blockIdx.x;      // 0..7
  int i0 = blockIdx.y * 8;  // i tile base
  int tid = threadIdx.x;
  int w = tid >> 6, l = tid & 63;
  int j = jc * 256 + tid;

  __shared__ float zsh[64][8];   // [k][r]  z
  __shared__ float zqh[64][8];   // [k][r]  z^2 (same rounding as in-loop z*z)
  if (tid < 128) {
    int k = tid >> 1, r0 = (tid & 1) * 4;
#pragma unroll
    for (int r = 0; r < 4; ++r) {
      float z = zs[(i0 + r0 + r) * NL + k];
      zsh[k][r0 + r] = z;
      zqh[k][r0 + r] = z * z;
    }
  }
  __syncthreads();

  // ---------------- K2 phase (identical math/order to round-2) -----------
  float accv[8];
  float q = QC2[j];
#pragma unroll
  for (int r = 0; r < 8; ++r) accv[r] = q;
  for (int k = 0; k < 64; ++k) {
    float2 am = AM2T[k * NB + j];                   // (a2, c1) per-thread
    const float4* z4 = (const float4*)&zsh[k][0];   // wave-uniform -> bcast
    const float4* q4 = (const float4*)&zqh[k][0];
    float4 za = z4[0], zb = z4[1];
    float4 qa = q4[0], qb = q4[1];
    float zk[8] = {za.x, za.y, za.z, za.w, zb.x, zb.y, zb.z, zb.w};
    float zz[8] = {qa.x, qa.y, qa.z, qa.w, qb.x, qb.y, qb.z, qb.w};
#pragma unroll
    for (int r = 0; r < 8; ++r) {
      accv[r] = fmaf(zz[r], am.x, accv[r]);  // == fmaf(zk*zk, a2, acc)
      accv[r] = fmaf(zk[r], am.y, accv[r]);  // == fmaf(zk,    c1, acc)
    }
  }
  __shared__ float lm[4][8], ls[4][8];
  float Mt[8];
#pragma unroll
  for (int r = 0; r < 8; ++r) {
    float mx = wredmax(accv[r]);
    if (l == 0) lm[w][r] = mx;
  }
  __syncthreads();
#pragma unroll
  for (int r = 0; r < 8; ++r)
    Mt[r] = fmaxf(fmaxf(lm[0][r], lm[1][r]), fmaxf(lm[2][r], lm[3][r]));
#pragma unroll
  for (int r = 0; r < 8; ++r) {
    float ss = wredsum(__builtin_amdgcn_exp2f(accv[r] - Mt[r]));
    if (l == 0) ls[w][r] = ss;
  }
  __syncthreads();
  if (tid == 0) {
#pragma unroll
    for (int r = 0; r < 8; ++r) {
      TPM[(i0 + r) * 8 + jc] = Mt[r];
      TPS[(i0 + r) * 8 + jc] = ls[0][r] + ls[1][r] + ls[2][r] + ls[3][r];
    }
  }

  // ---------------- K3 phase (identical math/order; float4 coeffs) -------
  float zr[8];
#pragma unroll
  for (int r = 0; r < 8; ++r) zr[r] = zs[(i0 + r) * NL + l];
  float S[8];
#pragma unroll
  for (int r = 0; r < 8; ++r) S[r] = 0.0f;
  const float4* p = PK2 + (size_t)(jc * 256 + w * 64) * NL + l;
#pragma unroll 4
  for (int jj = 0; jj < 64; ++jj) {
    float4 c = p[(size_t)jj * NL];
#pragma unroll
    for (int r = 0; r < 8; ++r) {
      float lp2 = fmaf(fmaf(zr[r], c.x, c.y), zr[r], c.z);
      S[r] += __builtin_amdgcn_exp2f(lp2);
    }
  }
  __shared__ float lss[4][8][64];
#pragma unroll
  for (int r = 0; r < 8; ++r) lss[w][r][l] = S[r];
  __syncthreads();
  for (int pp = tid; pp < 512; pp += 256) {
    int r = pp >> 6, ll = pp & 63;
    float Sc = lss[0][r][ll] + lss[1][r][ll] + lss[2][r][ll] + lss[3][r][ll];
    SP[((size_t)jc * NB + (i0 + r)) * NL + ll] = Sc;
  }
}

// K4: per-i: sum 8 j-chunk partials per (i,l) -> log2, sum over l (+64*BVAL),
// LSE-merge the 8 t-chunks -> log_qz; write per-i contribution. 1 wave per i.
__global__ __launch_bounds__(256) void k4_fin(const float* __restrict__ SP,
                                              const float* __restrict__ TPM,
                                              const float* __restrict__ TPS,
                                              float* __restrict__ PERI) {
  int tid = threadIdx.x;
  int w = tid >> 6, l = tid & 63;
  int i = blockIdx.x * 4 + w;
  float S = 0.0f;
#pragma unroll
  for (int s = 0; s < 8; ++s) S += SP[((size_t)s * NB + i) * NL + l];
  float val = __builtin_amdgcn_logf(S);  // log2
  float lqp2 = wredsum(val) + 64.0f * BVAL;
  float tm = (l < 8) ? TPM[i * 8 + l] : -1e30f;
  float ts = (l < 8) ? TPS[i * 8 + l] : 0.0f;
  float Mt = wredmax(tm);
  float St = wredsum(ts * __builtin_amdgcn_exp2f(tm - Mt));
  float lqz2 = Mt + __builtin_amdgcn_logf(St);
  if (l == 0) PERI[i] = lqz2 - lqp2;
}

// K5: final scalar. sum KLP[512], sum PERI[2048].
__global__ __launch_bounds__(256) void k5_out(const float* __restrict__ KLP,
                                              const float* __restrict__ PERI,
                                              float* __restrict__ out) {
  int tid = threadIdx.x;
  float a = 0.0f, b = 0.0f;
  for (int x = tid; x < 512; x += 256) a += KLP[x];
  for (int x = tid; x < 2048; x += 256) b += PERI[x];
  float ra = wredsum(a), rb = wredsum(b);
  __shared__ float sa[4], sb[4];
  if ((tid & 63) == 0) {
    sa[tid >> 6] = ra;
    sb[tid >> 6] = rb;
  }
  __syncthreads();
  if (tid == 0) {
    const float LN2 = 0.6931471805599453f;
    float ka = sa[0] + sa[1] + sa[2] + sa[3];
    float kb = sb[0] + sb[1] + sb[2] + sb[3];
    out[0] = ka + 5.0f * LN2 * kb * (1.0f / (float)NB);
  }
}

extern "C" void kernel_launch(void* const* d_in, const int* in_sizes, int n_in,
                              void* d_out, int out_size, void* d_ws, size_t ws_size,
                              hipStream_t stream) {
  const float* kl = (const float*)d_in[0];
  const float* zm = (const float*)d_in[1];
  const float* zlv = (const float*)d_in[2];
  const float* zs = (const float*)d_in[3];
  float* ws = (float*)d_ws;

  float* PK2 = ws;                  // 4*NE
  float* AM2T = PK2 + 4 * NE;       // 2*NE (interleaved a2,c1 transposed)
  float* QC2 = AM2T + 2 * NE;       // NB
  float* SP = QC2 + NB;             // 8*NE
  float* TPM = SP + 8 * NE;         // NB*8
  float* TPS = TPM + NB * 8;        // NB*8
  float* KLP = TPS + NB * 8;        // 512
  float* PERI = KLP + 512;          // NB     (total ~7.3 MB)

  k1_pre<<<NE / 256, 256, 0, stream>>>(kl, zm, zlv, (float4*)PK2,
                                       (float2*)AM2T, QC2, KLP);
  k23<<<dim3(8, NB / 8), 256, 0, stream>>>(zs, (const float2*)AM2T, QC2,
                                           (const float4*)PK2, TPM, TPS, SP);
  k4_fin<<<NB / 4, 256, 0, stream>>>(SP, TPM, TPS, PERI);
  k5_out<<<1, 256, 0, stream>>>(KLP, PERI, (float*)d_out);
}

// Round 7
// 128.204 us; speedup vs baseline: 1.1046x; 1.0016x over previous
//
#include <hip/hip_runtime.h>
#include <math.h>

// B=2048, L=64. out = sum(kl) + (BETA-1)*mean_i(log_qz_i - log_qz_product_i)
// lp2[i,j,l] = lp/ln2 = a2*d^2 + b2, d = z_i_l - m_j_l, a2 = -0.5/ln2*exp(-lv) < 0
// Single-pass LSE with constant shift BVAL (valid since lp2 <= b2 << BVAL).
// Horner: lp2 - BVAL = fma(fma(z, a2, c1), z, c0'), c1=-2*a2*m, c0'=a2*m^2+b2-BVAL.
//
// Round-7: r6 (best, k23=69.4us, VALUBusy 67%) + ONE change: unroll K2's
// k-loop by 8. Audit: busy cycles (~111K/SIMD) are near the static-instruction
// floor; the 33% idle matches K2's un-unrolled k-loop exposing ~170cy of L2
// latency per iteration (1 float2 load in flight vs 32cy of fma). 8 loads in
// flight hides it (K3's loop already has unroll 4 and stays busy).
// ~+16 VGPR (-> ~48), still under the 64-VGPR occupancy cliff.
// Same values, same reduction order -> bit-identical output.

#define NB 2048
#define NL 64
#define NE (NB * NL)
#define BVAL 12.0f

__device__ __forceinline__ float wredsum(float v) {
#pragma unroll
  for (int o = 32; o; o >>= 1) v += __shfl_xor(v, o, 64);
  return v;
}
__device__ __forceinline__ float wredmax(float v) {
#pragma unroll
  for (int o = 32; o; o >>= 1) v = fmaxf(v, __shfl_xor(v, o, 64));
  return v;
}

// K1: packed Horner coeffs (a2,c1,c0',0) for the K3 path, interleaved (a2,c1)
// transposed array + qc2 for the K2 path, per-block kl partial sums.
__global__ __launch_bounds__(256) void k1_pre(const float* __restrict__ kl,
                                              const float* __restrict__ zm,
                                              const float* __restrict__ zlv,
                                              float4* __restrict__ PK2,
                                              float2* __restrict__ AM2T,
                                              float* __restrict__ QC2,
                                              float* __restrict__ KLP) {
  const float INVLN2 = 1.4426950408889634f;
  const float LOG2PI = 1.8378770664093453f;
  int tid = threadIdx.x;
  int e = blockIdx.x * 256 + tid;  // < NE
  int j = e >> 6, l = e & 63;
  float lv = zlv[e], m = zm[e];
  float a2 = -0.5f * INVLN2 * __expf(-lv);
  float b2 = -0.5f * INVLN2 * (lv + LOG2PI);
  float c1 = -2.0f * a2 * m;
  float c0 = fmaf(a2 * m, m, b2);  // true a2*m^2 + b2
  PK2[e] = make_float4(a2, c1, c0 - BVAL, 0.0f);
  AM2T[l * NB + j] = make_float2(a2, c1);
  float q = wredsum(c0);  // sum_l (a2 m^2 + b2) for this j (one j per wave)
  if (l == 0) QC2[j] = q;
  float ks = wredsum(kl[e]);
  __shared__ float sk[4];
  if (l == 0) sk[tid >> 6] = ks;
  __syncthreads();
  if (tid == 0) KLP[blockIdx.x] = sk[0] + sk[1] + sk[2] + sk[3];
}

// Fused K2+K3 (independent phases, same grid, no cross-block comm).
// grid (8 j-chunks, 256 i-tiles), 256 thr.
// K2 phase: thread = one j, 8 i's; z and z^2 tiles staged in LDS; k-loop
// unrolled x8 so 8 AM2T loads are in flight (L2 latency hiding).
// K3 phase: thread = (wave w, lane l); 64 j's per wave, 8 i's per thread.
// Linear block id = jc + 8*it -> XCD = bid%8 = jc: each XCD streams only its
// own jc-chunk of PK2/AM2T (L2 locality); keep this mapping.
__global__ __launch_bounds__(256) void k23(const float* __restrict__ zs,
                                           const float2* __restrict__ AM2T,
                                           const float* __restrict__ QC2,
                                           const float4* __restrict__ PK2,
                                           float* __restrict__ TPM,
                                           float* __restrict__ TPS,
                                           float* __restrict__ SP) {
  int jc = blockIdx.x;      // 0..7
  int i0 = blockIdx.y * 8;  // i tile base
  int tid = threadIdx.x;
  int w = tid >> 6, l = tid & 63;
  int j = jc * 256 + tid;

  __shared__ float zsh[64][8];   // [k][r]  z
  __shared__ float zqh[64][8];   // [k][r]  z^2 (same rounding as in-loop z*z)
  if (tid < 128) {
    int k = tid >> 1, r0 = (tid & 1) * 4;
#pragma unroll
    for (int r = 0; r < 4; ++r) {
      float z = zs[(i0 + r0 + r) * NL + k];
      zsh[k][r0 + r] = z;
      zqh[k][r0 + r] = z * z;
    }
  }
  __syncthreads();

  // ---------------- K2 phase (identical math/order to r6; unroll 8) ------
  float accv[8];
  float q = QC2[j];
#pragma unroll
  for (int r = 0; r < 8; ++r) accv[r] = q;
#pragma unroll 8
  for (int k = 0; k < 64; ++k) {
    float2 am = AM2T[k * NB + j];                   // (a2, c1) per-thread
    const float4* z4 = (const float4*)&zsh[k][0];   // wave-uniform -> bcast
    const float4* q4 = (const float4*)&zqh[k][0];
    float4 za = z4[0], zb = z4[1];
    float4 qa = q4[0], qb = q4[1];
    float zk[8] = {za.x, za.y, za.z, za.w, zb.x, zb.y, zb.z, zb.w};
    float zz[8] = {qa.x, qa.y, qa.z, qa.w, qb.x, qb.y, qb.z, qb.w};
#pragma unroll
    for (int r = 0; r < 8; ++r) {
      accv[r] = fmaf(zz[r], am.x, accv[r]);  // == fmaf(zk*zk, a2, acc)
      accv[r] = fmaf(zk[r], am.y, accv[r]);  // == fmaf(zk,    c1, acc)
    }
  }
  __shared__ float lm[4][8], ls[4][8];
  float Mt[8];
#pragma unroll
  for (int r = 0; r < 8; ++r) {
    float mx = wredmax(accv[r]);
    if (l == 0) lm[w][r] = mx;
  }
  __syncthreads();
#pragma unroll
  for (int r = 0; r < 8; ++r)
    Mt[r] = fmaxf(fmaxf(lm[0][r], lm[1][r]), fmaxf(lm[2][r], lm[3][r]));
#pragma unroll
  for (int r = 0; r < 8; ++r) {
    float ss = wredsum(__builtin_amdgcn_exp2f(accv[r] - Mt[r]));
    if (l == 0) ls[w][r] = ss;
  }
  __syncthreads();
  if (tid == 0) {
#pragma unroll
    for (int r = 0; r < 8; ++r) {
      TPM[(i0 + r) * 8 + jc] = Mt[r];
      TPS[(i0 + r) * 8 + jc] = ls[0][r] + ls[1][r] + ls[2][r] + ls[3][r];
    }
  }

  // ---------------- K3 phase (identical math/order; float4 coeffs) -------
  float zr[8];
#pragma unroll
  for (int r = 0; r < 8; ++r) zr[r] = zs[(i0 + r) * NL + l];
  float S[8];
#pragma unroll
  for (int r = 0; r < 8; ++r) S[r] = 0.0f;
  const float4* p = PK2 + (size_t)(jc * 256 + w * 64) * NL + l;
#pragma unroll 4
  for (int jj = 0; jj < 64; ++jj) {
    float4 c = p[(size_t)jj * NL];
#pragma unroll
    for (int r = 0; r < 8; ++r) {
      float lp2 = fmaf(fmaf(zr[r], c.x, c.y), zr[r], c.z);
      S[r] += __builtin_amdgcn_exp2f(lp2);
    }
  }
  __shared__ float lss[4][8][64];
#pragma unroll
  for (int r = 0; r < 8; ++r) lss[w][r][l] = S[r];
  __syncthreads();
  for (int pp = tid; pp < 512; pp += 256) {
    int r = pp >> 6, ll = pp & 63;
    float Sc = lss[0][r][ll] + lss[1][r][ll] + lss[2][r][ll] + lss[3][r][ll];
    SP[((size_t)jc * NB + (i0 + r)) * NL + ll] = Sc;
  }
}

// K4: per-i: sum 8 j-chunk partials per (i,l) -> log2, sum over l (+64*BVAL),
// LSE-merge the 8 t-chunks -> log_qz; write per-i contribution. 1 wave per i.
__global__ __launch_bounds__(256) void k4_fin(const float* __restrict__ SP,
                                              const float* __restrict__ TPM,
                                              const float* __restrict__ TPS,
                                              float* __restrict__ PERI) {
  int tid = threadIdx.x;
  int w = tid >> 6, l = tid & 63;
  int i = blockIdx.x * 4 + w;
  float S = 0.0f;
#pragma unroll
  for (int s = 0; s < 8; ++s) S += SP[((size_t)s * NB + i) * NL + l];
  float val = __builtin_amdgcn_logf(S);  // log2
  float lqp2 = wredsum(val) + 64.0f * BVAL;
  float tm = (l < 8) ? TPM[i * 8 + l] : -1e30f;
  float ts = (l < 8) ? TPS[i * 8 + l] : 0.0f;
  float Mt = wredmax(tm);
  float St = wredsum(ts * __builtin_amdgcn_exp2f(tm - Mt));
  float lqz2 = Mt + __builtin_amdgcn_logf(St);
  if (l == 0) PERI[i] = lqz2 - lqp2;
}

// K5: final scalar. sum KLP[512], sum PERI[2048].
__global__ __launch_bounds__(256) void k5_out(const float* __restrict__ KLP,
                                              const float* __restrict__ PERI,
                                              float* __restrict__ out) {
  int tid = threadIdx.x;
  float a = 0.0f, b = 0.0f;
  for (int x = tid; x < 512; x += 256) a += KLP[x];
  for (int x = tid; x < 2048; x += 256) b += PERI[x];
  float ra = wredsum(a), rb = wredsum(b);
  __shared__ float sa[4], sb[4];
  if ((tid & 63) == 0) {
    sa[tid >> 6] = ra;
    sb[tid >> 6] = rb;
  }
  __syncthreads();
  if (tid == 0) {
    const float LN2 = 0.6931471805599453f;
    float ka = sa[0] + sa[1] + sa[2] + sa[3];
    float kb = sb[0] + sb[1] + sb[2] + sb[3];
    out[0] = ka + 5.0f * LN2 * kb * (1.0f / (float)NB);
  }
}

extern "C" void kernel_launch(void* const* d_in, const int* in_sizes, int n_in,
                              void* d_out, int out_size, void* d_ws, size_t ws_size,
                              hipStream_t stream) {
  const float* kl = (const float*)d_in[0];
  const float* zm = (const float*)d_in[1];
  const float* zlv = (const float*)d_in[2];
  const float* zs = (const float*)d_in[3];
  float* ws = (float*)d_ws;

  float* PK2 = ws;                  // 4*NE
  float* AM2T = PK2 + 4 * NE;       // 2*NE (interleaved a2,c1 transposed)
  float* QC2 = AM2T + 2 * NE;       // NB
  float* SP = QC2 + NB;             // 8*NE
  float* TPM = SP + 8 * NE;         // NB*8
  float* TPS = TPM + NB * 8;        // NB*8
  float* KLP = TPS + NB * 8;        // 512
  float* PERI = KLP + 512;          // NB     (total ~7.3 MB)

  k1_pre<<<NE / 256, 256, 0, stream>>>(kl, zm, zlv, (float4*)PK2,
                                       (float2*)AM2T, QC2, KLP);
  k23<<<dim3(8, NB / 8), 256, 0, stream>>>(zs, (const float2*)AM2T, QC2,
                                           (const float4*)PK2, TPM, TPS, SP);
  k4_fin<<<NB / 4, 256, 0, stream>>>(SP, TPM, TPS, PERI);
  k5_out<<<1, 256, 0, stream>>>(KLP, PERI, (float*)d_out);
}